// Round 8
// baseline (439.659 us; speedup 1.0000x reference)
//
#include <hip/hip_runtime.h>
#include <hip/hip_cooperative_groups.h>
#include <math.h>

namespace cg = cooperative_groups;

// ManifoldAlignmentLoss: B=256, D=512, N=50000, A=8, K=5
// R8: ONE cooperative dispatch, grid.sync() between phases.
//   Phase A: blocks [0,196)   match rows -> pair regions + (blk,b) rank/counts
//            blocks [196,452) z inverse norms (dot uses raw z * invnorms)
//            blocks [452,1024) sentinel-init sims buckets; zero out
//   Phase B: 4096 waves, wave-per-slot dot, dest = b*3136 + blk*16 + rank
//   Phase C: blocks [0,256) wave 0: bucket top-5, atomicAdd(out)
// Rationale: R3-R7 show match+dot "cost" ~42-55us invariant to structure while
// pipe math says ~12us; either inter-dispatch drains or in-kernel stalls. One
// dispatch kills all drains AND forces the kernel into the top-5 counters.

constexpr int D = 512;
constexpr int A = 8;
constexpr int K_NEI = 5;
constexpr int CAPB = 16;          // per-(blk,b) bucket slots (mean 0.66)
constexpr int CAP_BLK = 256;      // per-block pair region
constexpr int LDS_PAIR_CAP = 512;
constexpr int GRID = 1024;        // 4 blocks/CU @ 256 CUs
constexpr int TPB = 256;

__device__ __forceinline__ float wave_reduce_add(float v) {
    #pragma unroll
    for (int m = 1; m < 64; m <<= 1) v += __shfl_xor(v, m, 64);
    return v;
}

__global__ void __launch_bounds__(TPB, 4) mega_kernel(
    const float* __restrict__ z, const int* __restrict__ tattr,
    const float* __restrict__ train, const int* __restrict__ trattr,
    float* __restrict__ zinv, unsigned* __restrict__ pairs,
    int* __restrict__ cntblk, int* __restrict__ h,
    float* __restrict__ sims, float* __restrict__ out,
    int N, int NBLK, int Bt)
{
    cg::grid_group grid = cg::this_grid();
    const int bid = blockIdx.x;
    const int tid = threadIdx.x;
    const int lane = tid & 63;
    const int wv = tid >> 6;
    const int BSTRIDE = NBLK * CAPB;          // 3136
    const int SIMS_TOT = Bt * BSTRIDE;        // 802816

    __shared__ unsigned s_tp[256];
    __shared__ unsigned s_pairs[LDS_PAIR_CAP];
    __shared__ int s_hist[256];
    __shared__ int s_cnt;

    // ===================== Phase A =====================
    if (bid < NBLK) {
        // ---- match: one train row per thread vs all 256 targets ----
        const int n = bid * 256 + tid;
        {
            const int4* t4 = (const int4*)(tattr + (size_t)tid * A);
            const int4 x = t4[0], y = t4[1];
            s_tp[tid] = ((unsigned)x.x & 0xFu)        | (((unsigned)x.y & 0xFu) << 4)
                      | (((unsigned)x.z & 0xFu) << 8)  | (((unsigned)x.w & 0xFu) << 12)
                      | (((unsigned)y.x & 0xFu) << 16) | (((unsigned)y.y & 0xFu) << 20)
                      | (((unsigned)y.z & 0xFu) << 24) | (((unsigned)y.w & 0xFu) << 28);
        }
        s_hist[tid] = 0;
        if (tid == 0) s_cnt = 0;
        __syncthreads();

        if (n < N) {
            const int4* a4 = (const int4*)(trattr + (size_t)n * A);
            const int4 x = a4[0], y = a4[1];
            const unsigned p =
                 ((unsigned)x.x & 0xFu)        | (((unsigned)x.y & 0xFu) << 4)
               | (((unsigned)x.z & 0xFu) << 8)  | (((unsigned)x.w & 0xFu) << 12)
               | (((unsigned)y.x & 0xFu) << 16) | (((unsigned)y.y & 0xFu) << 20)
               | (((unsigned)y.z & 0xFu) << 24) | (((unsigned)y.w & 0xFu) << 28);

            const uint4* tp4 = (const uint4*)s_tp;
            #pragma unroll 4
            for (int bq = 0; bq < 64; bq++) {
                const uint4 t = tp4[bq];
                #pragma unroll
                for (int j = 0; j < 4; j++) {
                    const unsigned tv = (j == 0) ? t.x : (j == 1) ? t.y
                                      : (j == 2) ? t.z : t.w;
                    const unsigned yv = p ^ tv;
                    // hi bit of each nibble set iff nibble nonzero
                    const unsigned nzhi =
                        ((((yv & 0x77777777u) + 0x77777777u) | yv) & 0x88888888u);
                    if (__popc(nzhi) <= 1) {   // >= A-1 matching attrs
                        const int b = bq * 4 + j;
                        const int rank = atomicAdd(&s_hist[b], 1);   // LDS
                        if (rank < CAPB) {
                            const int idx = atomicAdd(&s_cnt, 1);    // LDS
                            if (idx < LDS_PAIR_CAP)
                                s_pairs[idx] = ((unsigned)n << 16)
                                             | ((unsigned)rank << 8) | (unsigned)b;
                        }
                    }
                }
            }
        }
        __syncthreads();
        h[bid * 256 + tid] = s_hist[tid];
        const int cnt = min(s_cnt, min(LDS_PAIR_CAP, CAP_BLK));
        if (tid == 0) cntblk[bid] = cnt;
        for (int i = tid; i < cnt; i += 256)
            pairs[bid * CAP_BLK + i] = s_pairs[i];
    } else if (bid < NBLK + 256) {
        // ---- z inverse norms: one b per block, wave 0 ----
        if (tid < 64) {
            const int b = bid - NBLK;
            const float4* zrow = (const float4*)(z + (size_t)b * D);
            const float4 v0 = zrow[tid * 2 + 0];
            const float4 v1 = zrow[tid * 2 + 1];
            float ss = v0.x*v0.x + v0.y*v0.y + v0.z*v0.z + v0.w*v0.w
                     + v1.x*v1.x + v1.y*v1.y + v1.z*v1.z + v1.w*v1.w;
            ss = wave_reduce_add(ss);
            if (tid == 0) zinv[b] = 1.0f / fmaxf(sqrtf(ss), 1e-12f);
        }
    } else {
        // ---- sentinel-init sims (float4 grid-stride over tail blocks) ----
        if (bid == NBLK + 256 && tid == 0) out[0] = 0.0f;
        float4* s4 = (float4*)sims;
        const int n4 = SIMS_TOT >> 2;
        const int nblocks = GRID - (NBLK + 256);
        const float4 sent = make_float4(-1e30f, -1e30f, -1e30f, -1e30f);
        for (int i = (bid - NBLK - 256) * TPB + tid; i < n4; i += nblocks * TPB)
            s4[i] = sent;
    }

    grid.sync();

    // ===================== Phase B: dot =====================
    {
        const int w = bid * 4 + wv;            // 4096 waves
        const int TOT = NBLK * CAP_BLK;        // 50176 slots
        for (int slot = w; slot < TOT; slot += GRID * 4) {
            const int blk = slot >> 8;
            const int idx = slot & (CAP_BLK - 1);
            if (idx >= cntblk[blk]) continue;
            const unsigned pr = pairs[slot];
            const int n    = (int)(pr >> 16);
            const int b    = (int)(pr & 255u);
            const int rank = (int)((pr >> 8) & 255u);
            const float4* r4 = (const float4*)(train + (size_t)n * D);
            const float4* z4 = (const float4*)(z     + (size_t)b * D);
            const float4 r0 = r4[lane * 2 + 0];
            const float4 r1 = r4[lane * 2 + 1];
            const float4 z0 = z4[lane * 2 + 0];
            const float4 z1 = z4[lane * 2 + 1];
            float ss = r0.x*r0.x + r0.y*r0.y + r0.z*r0.z + r0.w*r0.w
                     + r1.x*r1.x + r1.y*r1.y + r1.z*r1.z + r1.w*r1.w;
            float dd = r0.x*z0.x + r0.y*z0.y + r0.z*z0.z + r0.w*z0.w
                     + r1.x*z1.x + r1.y*z1.y + r1.z*z1.z + r1.w*z1.w;
            #pragma unroll
            for (int m = 1; m < 64; m <<= 1) {
                ss += __shfl_xor(ss, m, 64);
                dd += __shfl_xor(dd, m, 64);
            }
            if (lane == 0)
                sims[(size_t)b * BSTRIDE + blk * CAPB + rank] =
                    dd * (1.0f / fmaxf(sqrtf(ss), 1e-12f)) * zinv[b];
        }
    }

    grid.sync();

    // ===================== Phase C: topk =====================
    if (bid < Bt && tid < 64) {
        const int b = bid;
        // true match count: sum h column
        int c = 0;
        for (int blk = lane; blk < NBLK; blk += 64) c += h[blk * 256 + b];
        #pragma unroll
        for (int m = 1; m < 64; m <<= 1) c += __shfl_xor(c, m, 64);

        // per-lane top-5 insertion over the bucket (sentinels never insert)
        float top[K_NEI];
        #pragma unroll
        for (int k = 0; k < K_NEI; k++) top[k] = -1e30f;
        const float* buf = sims + (size_t)b * BSTRIDE;
        for (int i = lane; i < BSTRIDE; i += 64) {
            const float v = buf[i];
            if (v > top[K_NEI - 1]) {
                top[K_NEI - 1] = v;
                #pragma unroll
                for (int k = K_NEI - 1; k > 0; k--)
                    if (top[k] > top[k - 1]) {
                        float t = top[k]; top[k] = top[k - 1]; top[k - 1] = t;
                    }
            }
        }

        // 5-round wave max-eliminate
        float s = 0.0f;
        #pragma unroll
        for (int r = 0; r < K_NEI; r++) {
            float M = top[0];
            #pragma unroll
            for (int m = 1; m < 64; m <<= 1) M = fmaxf(M, __shfl_xor(M, m, 64));
            s += fmaxf(M, 0.0f);   // zeros from unmatched entries dominate negatives
            const unsigned long long bal = __ballot(top[0] == M);
            const int first = __ffsll(bal) - 1;
            if (lane == first) {
                #pragma unroll
                for (int k = 0; k < K_NEI - 1; k++) top[k] = top[k + 1];
                top[K_NEI - 1] = -1e30f;
            }
        }

        if (lane == 0) {
            const float contrib = (c >= K_NEI) ? (1.0f - s * (1.0f / K_NEI)) : 0.0f;
            atomicAdd(out, contrib / (float)Bt);
        }
    }
}

extern "C" void kernel_launch(void* const* d_in, const int* in_sizes, int n_in,
                              void* d_out, int out_size, void* d_ws, size_t ws_size,
                              hipStream_t stream)
{
    const float* z      = (const float*)d_in[0];   // [B, D] f32
    const int*   tattr  = (const int*)d_in[1];     // [B, A] i32
    const float* train  = (const float*)d_in[2];   // [N, D] f32
    const int*   trattr = (const int*)d_in[3];     // [N, A] i32
    float* out = (float*)d_out;

    const int B = in_sizes[0] / D;        // 256
    const int N = in_sizes[2] / D;        // 50000
    const int NBLK = (N + 255) / 256;     // 196
    const int TOT = NBLK * CAP_BLK;       // 50176

    // ws layout
    char* ws = (char*)d_ws;
    float*    zinv    = (float*)ws;    ws += ((size_t)B * sizeof(float) + 63) & ~63ull;
    int*      h       = (int*)ws;      ws += (size_t)NBLK * 256 * sizeof(int);
    int*      cntblk  = (int*)ws;      ws += ((size_t)NBLK * sizeof(int) + 63) & ~63ull;
    unsigned* pairs   = (unsigned*)ws; ws += (size_t)TOT * sizeof(unsigned);
    float*    sims    = (float*)ws;

    int n_arg = N, nblk_arg = NBLK, b_arg = B;
    void* args[] = { (void*)&z, (void*)&tattr, (void*)&train, (void*)&trattr,
                     (void*)&zinv, (void*)&pairs, (void*)&cntblk, (void*)&h,
                     (void*)&sims, (void*)&out,
                     (void*)&n_arg, (void*)&nblk_arg, (void*)&b_arg };
    hipLaunchCooperativeKernel((void*)mega_kernel, dim3(GRID), dim3(TPB),
                               args, 0, stream);
}

// Round 9
// 183.670 us; speedup vs baseline: 2.3937x; 2.3937x over previous
//
#include <hip/hip_runtime.h>
#include <math.h>

// ManifoldAlignmentLoss: B=256, D=512, N=50000, A=8, K=5
// R9 = R4 (best, 177.5us) with dot rewritten for 4-wide ILP:
//   each wave processes aligned groups of 4 pairs; one uint4 load gets 4 pair
//   descriptors; all 16 float4 row/z loads issue independently (4x the
//   in-flight bytes of R4's 2-deep pipeline); then 4 independent reductions.
// Falsified so far: wave count (R4), atomics (R5), shfl depth (R6/R7),
// dispatch gaps / cooperative fusion (R8: grid.sync spin = 300us, dead).

constexpr int D = 512;
constexpr int A = 8;
constexpr int K_NEI = 5;
constexpr int SLOTS = 512;        // per-b sim bucket capacity (mean ~130)
constexpr int CSTRIDE = 16;       // counter padding: 64B per counter line
constexpr int PAIR_CAP = 65536;   // global pair list capacity (mean ~33K)
constexpr int LDS_PAIR_CAP = 1024;
constexpr int DOT_BLOCKS = 1024;  // 4096 waves x 4 pairs-in-flight each

__device__ __forceinline__ float wave_reduce_add(float v) {
    #pragma unroll
    for (int m = 1; m < 64; m <<= 1) v += __shfl_xor(v, m, 64);
    return v;
}

// ---------------- prep: normalize z rows, pack target attrs, zero state ----
// grid = B blocks x 64 threads
__global__ __launch_bounds__(64) void prep_kernel(
    const float* __restrict__ z, const int* __restrict__ tattr,
    float* __restrict__ z_norm, unsigned* __restrict__ tpacked,
    int* __restrict__ counters, int* __restrict__ npairs,
    float* __restrict__ out)
{
    const int b = blockIdx.x;
    const int lane = threadIdx.x;
    const float4* zrow = (const float4*)(z + (size_t)b * D);
    float4 v0 = zrow[lane * 2 + 0];
    float4 v1 = zrow[lane * 2 + 1];
    float ss = v0.x*v0.x + v0.y*v0.y + v0.z*v0.z + v0.w*v0.w
             + v1.x*v1.x + v1.y*v1.y + v1.z*v1.z + v1.w*v1.w;
    ss = wave_reduce_add(ss);
    const float scale = 1.0f / fmaxf(sqrtf(ss), 1e-12f);
    v0.x *= scale; v0.y *= scale; v0.z *= scale; v0.w *= scale;
    v1.x *= scale; v1.y *= scale; v1.z *= scale; v1.w *= scale;
    float4* orow = (float4*)(z_norm + (size_t)b * D);
    orow[lane * 2 + 0] = v0;
    orow[lane * 2 + 1] = v1;
    if (lane == 0) {
        unsigned p = 0;
        #pragma unroll
        for (int a = 0; a < A; a++)
            p |= ((unsigned)tattr[b * A + a] & 0xFu) << (4 * a);
        tpacked[b] = p;
        counters[b * CSTRIDE] = 0;
        if (b == 0) { *npairs = 0; out[0] = 0.0f; }
    }
}

// ---------------- match: one thread per train row, compact pairs ----------
// grid = ceil(N/256) blocks x 256 threads
__global__ __launch_bounds__(256) void match_kernel(
    const int* __restrict__ trattr, const unsigned* __restrict__ tpacked,
    unsigned* __restrict__ pairs, int* __restrict__ npairs, int N)
{
    __shared__ unsigned s_tp[256];
    __shared__ unsigned s_pairs[LDS_PAIR_CAP];
    __shared__ int s_cnt, s_base;

    const int tid = threadIdx.x;
    const int n = blockIdx.x * 256 + tid;
    s_tp[tid] = tpacked[tid];
    if (tid == 0) s_cnt = 0;
    __syncthreads();

    if (n < N) {
        const int4* a4 = (const int4*)(trattr + (size_t)n * A);
        const int4 x = a4[0], y = a4[1];
        const unsigned p =
             ((unsigned)x.x & 0xFu)        | (((unsigned)x.y & 0xFu) << 4)
           | (((unsigned)x.z & 0xFu) << 8)  | (((unsigned)x.w & 0xFu) << 12)
           | (((unsigned)y.x & 0xFu) << 16) | (((unsigned)y.y & 0xFu) << 20)
           | (((unsigned)y.z & 0xFu) << 24) | (((unsigned)y.w & 0xFu) << 28);

        const uint4* tp4 = (const uint4*)s_tp;
        #pragma unroll 4
        for (int bq = 0; bq < 64; bq++) {
            const uint4 t = tp4[bq];
            #pragma unroll
            for (int j = 0; j < 4; j++) {
                const unsigned tv = (j == 0) ? t.x : (j == 1) ? t.y : (j == 2) ? t.z : t.w;
                const unsigned yv = p ^ tv;
                // hi bit of each nibble set iff nibble nonzero
                const unsigned nzhi = ((((yv & 0x77777777u) + 0x77777777u) | yv) & 0x88888888u);
                if (__popc(nzhi) <= 1) {   // >= A-1 matching attrs
                    const int idx = atomicAdd(&s_cnt, 1);
                    if (idx < LDS_PAIR_CAP)
                        s_pairs[idx] = ((unsigned)n << 8) | (unsigned)(bq * 4 + j);
                }
            }
        }
    }
    __syncthreads();
    const int cnt = min(s_cnt, LDS_PAIR_CAP);
    if (tid == 0) s_base = atomicAdd(npairs, cnt);
    __syncthreads();
    const int base = s_base;
    for (int i = tid; i < cnt; i += 256)
        if (base + i < PAIR_CAP) pairs[base + i] = s_pairs[i];
}

// ------- dot: 4 pairs in flight per wave (max gather MLP) -----------------
// grid = DOT_BLOCKS x 256 threads
__global__ __launch_bounds__(256) void dot_kernel(
    const float* __restrict__ train, const float* __restrict__ z_norm,
    const unsigned* __restrict__ pairs, const int* __restrict__ npairs,
    int* __restrict__ counters, float* __restrict__ simbuf)
{
    const int lane = threadIdx.x & 63;
    const int w = blockIdx.x * 4 + (threadIdx.x >> 6);
    const int nwaves = DOT_BLOCKS * 4;
    const int np = min(*npairs, PAIR_CAP);

    for (int i0 = w * 4; i0 < np; i0 += nwaves * 4) {
        // one uint4 load = 4 pair descriptors (i0 is 4-aligned)
        const uint4 p4 = ((const uint4*)pairs)[i0 >> 2];
        const unsigned prk[4] = { p4.x, p4.y, p4.z, p4.w };
        const int nv = np - i0;   // >=1 here; pairs beyond np are garbage

        // issue all row/z loads for up to 4 pairs back-to-back (independent)
        float4 r0[4], r1[4], z0[4], z1[4];
        #pragma unroll
        for (int k = 0; k < 4; k++) {
            if (k < nv) {
                const float4* r4 = (const float4*)(train  + (size_t)(prk[k] >> 8)   * D);
                const float4* z4 = (const float4*)(z_norm + (size_t)(prk[k] & 255u) * D);
                r0[k] = r4[lane * 2 + 0];
                r1[k] = r4[lane * 2 + 1];
                z0[k] = z4[lane * 2 + 0];
                z1[k] = z4[lane * 2 + 1];
            }
        }

        // 4 independent reductions
        float ss[4], dd[4];
        #pragma unroll
        for (int k = 0; k < 4; k++) {
            if (k < nv) {
                ss[k] = r0[k].x*r0[k].x + r0[k].y*r0[k].y + r0[k].z*r0[k].z + r0[k].w*r0[k].w
                      + r1[k].x*r1[k].x + r1[k].y*r1[k].y + r1[k].z*r1[k].z + r1[k].w*r1[k].w;
                dd[k] = r0[k].x*z0[k].x + r0[k].y*z0[k].y + r0[k].z*z0[k].z + r0[k].w*z0[k].w
                      + r1[k].x*z1[k].x + r1[k].y*z1[k].y + r1[k].z*z1[k].z + r1[k].w*z1[k].w;
            } else { ss[k] = 0.0f; dd[k] = 0.0f; }
        }
        #pragma unroll
        for (int m = 1; m < 64; m <<= 1) {
            #pragma unroll
            for (int k = 0; k < 4; k++) {
                ss[k] += __shfl_xor(ss[k], m, 64);
                dd[k] += __shfl_xor(dd[k], m, 64);
            }
        }

        if (lane == 0) {
            #pragma unroll
            for (int k = 0; k < 4; k++) {
                if (k < nv) {
                    const int b = (int)(prk[k] & 255u);
                    const float sim = dd[k] / fmaxf(sqrtf(ss[k]), 1e-12f);
                    const int idx = atomicAdd(&counters[b * CSTRIDE], 1);
                    if (idx < SLOTS) simbuf[(size_t)b * SLOTS + idx] = sim;
                }
            }
        }
    }
}

// ---------------- topk: one wave per b, 5x wave-max, atomic into out ------
// grid = 256 blocks x 64 threads
__global__ __launch_bounds__(64) void topk_kernel(
    const int* __restrict__ counters, const float* __restrict__ simbuf,
    float* __restrict__ out, int Bt)
{
    const int b = blockIdx.x;
    const int lane = threadIdx.x;
    const int cnt = counters[b * CSTRIDE];
    const int m = min(cnt, SLOTS);
    const float* buf = simbuf + (size_t)b * SLOTS;

    float v[8];
    #pragma unroll
    for (int k = 0; k < 8; k++) {
        const int i = lane + k * 64;
        v[k] = (i < m) ? buf[i] : -1e30f;
    }

    float s = 0.0f;
    #pragma unroll
    for (int r = 0; r < K_NEI; r++) {
        float best = v[0];
        #pragma unroll
        for (int k = 1; k < 8; k++) best = fmaxf(best, v[k]);
        float M = best;
        #pragma unroll
        for (int mm = 1; mm < 64; mm <<= 1) M = fmaxf(M, __shfl_xor(M, mm, 64));
        s += fmaxf(M, 0.0f);   // N-cnt exact zeros from unmatched entries dominate negatives
        const unsigned long long bal = __ballot(best == M);
        const int first = __ffsll(bal) - 1;
        if (lane == first) {
            if      (v[0] == M) v[0] = -1e30f;
            else if (v[1] == M) v[1] = -1e30f;
            else if (v[2] == M) v[2] = -1e30f;
            else if (v[3] == M) v[3] = -1e30f;
            else if (v[4] == M) v[4] = -1e30f;
            else if (v[5] == M) v[5] = -1e30f;
            else if (v[6] == M) v[6] = -1e30f;
            else                v[7] = -1e30f;
        }
    }

    if (lane == 0) {
        const float contrib = (cnt >= K_NEI) ? (1.0f - s * (1.0f / K_NEI)) : 0.0f;
        atomicAdd(out, contrib / (float)Bt);
    }
}

extern "C" void kernel_launch(void* const* d_in, const int* in_sizes, int n_in,
                              void* d_out, int out_size, void* d_ws, size_t ws_size,
                              hipStream_t stream)
{
    const float* z      = (const float*)d_in[0];   // [B, D] f32
    const int*   tattr  = (const int*)d_in[1];     // [B, A] i32
    const float* train  = (const float*)d_in[2];   // [N, D] f32
    const int*   trattr = (const int*)d_in[3];     // [N, A] i32
    float* out = (float*)d_out;

    const int B = in_sizes[0] / D;     // 256
    const int N = in_sizes[2] / D;     // 50000

    // ws layout
    char* ws = (char*)d_ws;
    float*    z_norm   = (float*)ws;    ws += (size_t)B * D * sizeof(float);
    unsigned* tpacked  = (unsigned*)ws; ws += (size_t)B * sizeof(unsigned);
    int*      counters = (int*)ws;      ws += (size_t)B * CSTRIDE * sizeof(int);
    float*    simbuf   = (float*)ws;    ws += (size_t)B * SLOTS * sizeof(float);
    int*      npairs   = (int*)ws;      ws += 64;
    unsigned* pairs    = (unsigned*)ws;

    prep_kernel<<<B, 64, 0, stream>>>(z, tattr, z_norm, tpacked, counters, npairs, out);
    match_kernel<<<(N + 255) / 256, 256, 0, stream>>>(trattr, tpacked, pairs, npairs, N);
    dot_kernel<<<DOT_BLOCKS, 256, 0, stream>>>(train, z_norm, pairs, npairs, counters, simbuf);
    topk_kernel<<<B, 64, 0, stream>>>(counters, simbuf, out, B);
}